// Round 13
// baseline (101.958 us; speedup 1.0000x reference)
//
#include <hip/hip_runtime.h>

typedef __attribute__((ext_vector_type(4))) float f32x4;
typedef __attribute__((ext_vector_type(8))) short bf16x8;

typedef __attribute__((address_space(3))) unsigned char lds_b;
typedef const __attribute__((address_space(1))) unsigned char glb_b;

__device__ __forceinline__ void gload_lds16(const void* g, void* l) {
  __builtin_amdgcn_global_load_lds((glb_b*)g, (lds_b*)l, 16, 0, 0);
}

__device__ __forceinline__ unsigned short f2bf(float f) {
  union { float f; unsigned int u; } v; v.f = f;
  unsigned int r = v.u + 0x7fffu + ((v.u >> 16) & 1u);
  return (unsigned short)(r >> 16);
}

// ---------------------------------------------------------------------------
// theta_prep: Tg[k][o][f] (XOR-swizzled) = bf16(Theta[k][f][o]). grid 1.
// ---------------------------------------------------------------------------
__global__ __launch_bounds__(256) void theta_prep_k(const float* __restrict__ Theta,
                                                    unsigned short* __restrict__ Tg) {
  const int tid = threadIdx.x;
#pragma unroll
  for (int j = 0; j < 12; ++j) {
    int i = tid + j * 256;              // 0..3071 float4 index
    int k = i >> 10, rr = i & 1023;
    int f = rr >> 4, o0 = (rr & 15) << 2;
    float4 v = *(const float4*)(Theta + ((size_t)(k * 64 + f)) * 64 + o0);
    float vv[4] = {v.x, v.y, v.z, v.w};
#pragma unroll
    for (int jj = 0; jj < 4; ++jj) {
      int o = o0 + jj;
      int byte = k * 8192 + o * 128 + ((((f >> 3) ^ (o & 7)) << 4) | ((f & 7) << 1));
      *(unsigned short*)((char*)Tg + byte) = f2bf(vv[jj]);
    }
  }
}

// ---------------------------------------------------------------------------
// prep_fused: blocks [0,1024) = prep_U (one per (b,mt)); [1024,3072) = prep_A.
//
// prep_U LDS is 3x smaller than round-10: Xl holds ONE t-group [tl4][m16][f64]
// (8KB); the tg loop re-loads the block's x float4s with r%3==tg each phase.
// First pass touches every 128B line (HBM FETCH unchanged); passes 2,3 hit
// the block's OWN L1/L2 (same CU -> same XCD, unlike the failed cross-block
// sharing of r9/r11). Total LDS 16.9KB (A-branch 17.4KB is the max) ->
// 8 blocks/CU instead of 4. Wave-private Uo staging + cooperative full-line
// stores (each b128 store = 8 full 128B lines) kept from round 10.
// U3 layout [b][k][mt][ot][16] unchanged.
// ---------------------------------------------------------------------------
__global__ __launch_bounds__(256) void prep_fused_k(const float* __restrict__ x,
                                                    const float* __restrict__ cheb,
                                                    const float* __restrict__ att,
                                                    const unsigned short* __restrict__ Tg,
                                                    unsigned short* __restrict__ A_ws,
                                                    unsigned short* __restrict__ U_ws) {
  __shared__ __align__(16) char smem[17408];   // U: Xl 8192 + Uo 8704 | A: 17408
  const int bid = blockIdx.x;
  const int tid = threadIdx.x;

  if (bid < 1024) {
    // ================= prep_U part =================
    unsigned short* Xl = (unsigned short*)smem;           // [tl4][m16][f64] swizzled
    unsigned short* Uo = (unsigned short*)(smem + 8192);  // [w4][o16][68]
    const int b = bid >> 5, mt = bid & 31;
    const int m0 = mt * 16;
    const int lane = tid & 63, w = tid >> 6;
    const int c = lane & 15, q = lane >> 4;
    const int og8 = lane >> 3, sub = lane & 7;

    // Theta fragments: 6 coalesced 16B loads (Tg L2-hot from pre-kernel)
    bf16x8 afr[3][2];
#pragma unroll
    for (int k = 0; k < 3; ++k)
#pragma unroll
      for (int h = 0; h < 2; ++h) {
        int g = h * 4 + q;
        afr[k][h] = *(const bf16x8*)((const char*)Tg +
                      k * 8192 + (w * 16 + c) * 128 + (((g ^ (c & 7)) << 4)));
      }

    const float* xb = x + ((size_t)(b * 512 + m0)) * 768;
    const size_t ureg = ((size_t)(b * 3) * 32 + mt) * 12288;
    unsigned short* Uw = Uo + w * 1088;         // wave-private staging

    for (int tg = 0; tg < 3; ++tg) {
      if (tg) __syncthreads();   // prev-tg Xl reads done before overwrite
      // stage this tg's Xl: float4 r = f*3 + tg  (e = f*12 + tg*4 + tl)
#pragma unroll
      for (int jj = 0; jj < 4; ++jj) {
        int idx = tid + jj * 256;               // 0..1023
        int m = idx >> 6, fi = idx & 63;
        float4 v = *(const float4*)(xb + (size_t)m * 768 + (fi * 3 + tg) * 4);
        float vv[4] = {v.x, v.y, v.z, v.w};
#pragma unroll
        for (int tl = 0; tl < 4; ++tl) {
          int byte = tl * 2048 + m * 128 +
                     ((((fi >> 3) ^ (m & 7)) << 4) | ((fi & 7) << 1));
          *(unsigned short*)((char*)Xl + byte) = f2bf(vv[tl]);
        }
      }
      __syncthreads();

      bf16x8 bfr[4][2];                         // reused across k
#pragma unroll
      for (int tl = 0; tl < 4; ++tl)
#pragma unroll
        for (int h = 0; h < 2; ++h) {
          int g = h * 4 + q;
          bfr[tl][h] = *(const bf16x8*)((char*)Xl +
                         tl * 2048 + c * 128 + (((g ^ (c & 7)) << 4)));
        }
#pragma unroll
      for (int k = 0; k < 3; ++k) {
        f32x4 acc[4];
#pragma unroll
        for (int tl = 0; tl < 4; ++tl) {
          f32x4 a = {0.f, 0.f, 0.f, 0.f};
          a = __builtin_amdgcn_mfma_f32_16x16x32_bf16(afr[k][0], bfr[tl][0], a, 0, 0, 0);
          acc[tl] = __builtin_amdgcn_mfma_f32_16x16x32_bf16(afr[k][1], bfr[tl][1], a, 0, 0, 0);
        }
        // stage into wave-private Uo rows (2-way banks, free)
#pragma unroll
        for (int tl = 0; tl < 4; ++tl)
#pragma unroll
          for (int r = 0; r < 4; ++r)
            Uw[(q * 4 + r) * 68 + tl * 16 + c] = f2bf(acc[tl][r]);
        // cooperative full-line store: each inst = 8 full 128B lines
        unsigned short* ub2 = U_ws + ureg + (size_t)k * 393216;
#pragma unroll
        for (int i = 0; i < 2; ++i) {
          int ol = i * 8 + og8;                 // wave-local o (0..15)
          bf16x8 v = *(const bf16x8*)(Uw + ol * 68 + sub * 8);
          *(bf16x8*)(ub2 + ((w * 16 + ol) * 12 + tg * 4) * 16 + sub * 8) = v;
        }
      }
    }
  } else {
    // ================= prep_A part =================
    float (*tile)[68] = (float(*)[68])smem;      // 64x68 fp32, 17.4KB
    const int id = bid - 1024;
    const int m0 = (id & 7) * 64, n0 = ((id >> 3) & 7) * 64, b = id >> 6;
    const int rm = tid >> 2;   // 0..63
    const int c4 = tid & 3;    // 0..3
    for (int k = 0; k < 3; ++k) {
      const float* cp = cheb + ((size_t)(k * 512 + m0 + rm)) * 512 + n0 + c4 * 16;
      const float* ap = att  + ((size_t)(b * 512 + m0 + rm)) * 512 + n0 + c4 * 16;
#pragma unroll
      for (int j = 0; j < 4; ++j) {
        float4 cc = *(const float4*)(cp + j * 4);
        float4 aa = *(const float4*)(ap + j * 4);
        float4 p; p.x = cc.x * aa.x; p.y = cc.y * aa.y; p.z = cc.z * aa.z; p.w = cc.w * aa.w;
        *(float4*)&tile[rm][c4 * 16 + j * 4] = p;
      }
      __syncthreads();
      unsigned int pk[8];
#pragma unroll
      for (int i = 0; i < 8; ++i) {
        float v0 = tile[c4 * 16 + 2 * i][rm];
        float v1 = tile[c4 * 16 + 2 * i + 1][rm];
        pk[i] = (unsigned int)f2bf(v0) | ((unsigned int)f2bf(v1) << 16);
      }
      unsigned short* op = A_ws + ((size_t)(b * 512 + n0 + rm)) * 1536 + k * 512 + m0 + c4 * 16;
      uint4 w0; w0.x = pk[0]; w0.y = pk[1]; w0.z = pk[2]; w0.w = pk[3];
      uint4 w1; w1.x = pk[4]; w1.y = pk[5]; w1.z = pk[6]; w1.w = pk[7];
      ((uint4*)op)[0] = w0;
      ((uint4*)op)[1] = w1;
      __syncthreads();
    }
  }
}

// ---------------------------------------------------------------------------
// gemm_k: out[b][n][ot] = relu( sum_{km} A_ws[b][n][km] * U3[...] )
// 128x128 tile, BK=64, 4 waves (2x2), mfma_f32_16x16x32_bf16.
// U3 [b][k][mt][ot][16]: per issue each mt-region is read as a contiguous
// 256B span (full lines). global_load_lds width=16 staging; XCD remap.
// ---------------------------------------------------------------------------
__global__ __launch_bounds__(256) void gemm_k(const unsigned short* __restrict__ A_ws,
                                              const unsigned short* __restrict__ U_ws,
                                              float* __restrict__ out) {
  __shared__ unsigned short At[128 * 64];
  __shared__ unsigned short Bt[128 * 64];
  const int hw = blockIdx.x;
  const int logical = (hw & 7) * 96 + (hw >> 3);
  const int b = logical / 24;
  const int rem = logical - b * 24;
  const int nb = (rem / 6) * 128;
  const int otb = (rem % 6) * 128;

  const int tid = threadIdx.x;
  const int lane = tid & 63, w = tid >> 6;
  const int wr = w >> 1, wc = w & 1;
  const int q = lane >> 4;   // 0..3
  const int c = lane & 15;   // 0..15

  const int rl = lane >> 3;            // row within 8-row group (== row&7)
  const int gsrc = (lane & 7) ^ rl;    // pre-swizzled source granule
  const int mi0 = (gsrc & 1) * 8;      // ushort offset within 16-m tile
  const int mtq = gsrc >> 1;           // m-tile offset within 64-m chunk
  f32x4 acc[4][4] = {};

  const int uOff = (otb + w * 8 + rl) * 16 + mi0;   // + i*32*16 per issue
  const unsigned short* aRow = A_ws + ((size_t)(b * 512 + nb + w * 8 + rl)) * 1536 + gsrc * 8;
  const int ldsRowBase = w * 8 * 64;

  for (int kt = 0; kt < 24; ++kt) {
    const int k = kt >> 3;
    const int mc = kt & 7;
    const unsigned short* uBase =
        U_ws + ((size_t)((b * 3 + k) * 32 + mc * 4 + mtq)) * 12288 + uOff;
#pragma unroll
    for (int i = 0; i < 4; ++i) {
      gload_lds16(aRow + (size_t)(i * 32) * 1536 + kt * 64, &At[ldsRowBase + i * 32 * 64]);
      gload_lds16(uBase + i * 512,                          &Bt[ldsRowBase + i * 32 * 64]);
    }
    __syncthreads();
#pragma unroll
    for (int h = 0; h < 2; ++h) {
      bf16x8 af[4], bfv[4];
#pragma unroll
      for (int mi = 0; mi < 4; ++mi) {
        int row = wr * 64 + mi * 16 + c;
        af[mi] = *(const bf16x8*)&At[row * 64 + (((h * 4 + q) ^ (row & 7)) << 3)];
      }
#pragma unroll
      for (int ni = 0; ni < 4; ++ni) {
        int row = wc * 64 + ni * 16 + c;
        bfv[ni] = *(const bf16x8*)&Bt[row * 64 + (((h * 4 + q) ^ (row & 7)) << 3)];
      }
#pragma unroll
      for (int mi = 0; mi < 4; ++mi)
#pragma unroll
        for (int ni = 0; ni < 4; ++ni)
          acc[mi][ni] = __builtin_amdgcn_mfma_f32_16x16x32_bf16(af[mi], bfv[ni], acc[mi][ni], 0, 0, 0);
    }
    __syncthreads();
  }
#pragma unroll
  for (int mi = 0; mi < 4; ++mi) {
#pragma unroll
    for (int r = 0; r < 4; ++r) {
      int n = nb + wr * 64 + mi * 16 + q * 4 + r;
      float* orow = out + ((size_t)(b * 512 + n)) * 768 + otb + wc * 64 + c;
#pragma unroll
      for (int ni = 0; ni < 4; ++ni)
        orow[ni * 16] = fmaxf(acc[mi][ni][r], 0.f);
    }
  }
}

// ---------------------------------------------------------------------------
// Fallback (exact fp32, no workspace): grid (512 n, 32 b), 256 threads.
// ---------------------------------------------------------------------------
__global__ __launch_bounds__(256) void fallback_k(const float* __restrict__ x,
                                                  const float* __restrict__ cheb,
                                                  const float* __restrict__ att,
                                                  const float* __restrict__ Theta,
                                                  float* __restrict__ out) {
  __shared__ float wsm[3][512];
  __shared__ float z[3][768];
  const int n = blockIdx.x, b = blockIdx.y;
  const int tid = threadIdx.x;
  for (int i = tid; i < 1536; i += 256) {
    int k = i >> 9, m = i & 511;
    wsm[k][m] = cheb[((size_t)(k * 512 + m)) * 512 + n] * att[((size_t)(b * 512 + m)) * 512 + n];
  }
  __syncthreads();
  float a0[3] = {0.f, 0.f, 0.f}, a1[3] = {0.f, 0.f, 0.f}, a2[3] = {0.f, 0.f, 0.f};
  const float* xb = x + (size_t)b * 512 * 768;
  for (int m = 0; m < 512; ++m) {
    float w0 = wsm[0][m], w1 = wsm[1][m], w2 = wsm[2][m];
    float x0 = xb[(size_t)m * 768 + tid];
    float x1 = xb[(size_t)m * 768 + tid + 256];
    float x2 = xb[(size_t)m * 768 + tid + 512];
    a0[0] += w0 * x0; a0[1] += w1 * x0; a0[2] += w2 * x0;
    a1[0] += w0 * x1; a1[1] += w1 * x1; a1[2] += w2 * x1;
    a2[0] += w0 * x2; a2[1] += w1 * x2; a2[2] += w2 * x2;
  }
#pragma unroll
  for (int k = 0; k < 3; ++k) {
    z[k][tid] = a0[k]; z[k][tid + 256] = a1[k]; z[k][tid + 512] = a2[k];
  }
  __syncthreads();
#pragma unroll
  for (int j = 0; j < 3; ++j) {
    int ot = tid + j * 256;
    int o = ot / 12, t = ot - o * 12;
    float s = 0.f;
    for (int k = 0; k < 3; ++k)
#pragma unroll
      for (int f = 0; f < 64; ++f)
        s += z[k][f * 12 + t] * Theta[((size_t)(k * 64 + f)) * 64 + o];
    out[((size_t)(b * 512 + n)) * 768 + ot] = fmaxf(s, 0.f);
  }
}

extern "C" void kernel_launch(void* const* d_in, const int* in_sizes, int n_in,
                              void* d_out, int out_size, void* d_ws, size_t ws_size,
                              hipStream_t stream) {
  const float* x     = (const float*)d_in[0];  // (32,512,64,12)
  const float* cheb  = (const float*)d_in[1];  // (3,512,512)
  const float* att   = (const float*)d_in[2];  // (32,512,512)
  const float* Theta = (const float*)d_in[3];  // (3,64,64)
  float* out = (float*)d_out;                  // (32,512,64,12)

  const size_t needA = (size_t)32 * 512 * 1536 * 2;       // 50,331,648
  const size_t needU = (size_t)32 * 3 * 768 * 512 * 2;    // 75,497,472
  const size_t needT = (size_t)3 * 64 * 64 * 2;           // 24,576

  if (ws_size >= needA + needU + needT) {
    unsigned short* A_ws = (unsigned short*)d_ws;
    unsigned short* U_ws = (unsigned short*)((char*)d_ws + needA);
    unsigned short* Tg   = (unsigned short*)((char*)d_ws + needA + needU);
    theta_prep_k<<<dim3(1), 256, 0, stream>>>(Theta, Tg);
    prep_fused_k<<<dim3(3072), 256, 0, stream>>>(x, cheb, att, Tg, A_ws, U_ws);
    gemm_k<<<dim3(768), 256, 0, stream>>>(A_ws, U_ws, out);
  } else {
    fallback_k<<<dim3(512, 32), 256, 0, stream>>>(x, cheb, att, Theta, out);
  }
}

// Round 14
// 92.446 us; speedup vs baseline: 1.1029x; 1.1029x over previous
//
#include <hip/hip_runtime.h>

typedef __attribute__((ext_vector_type(4))) float f32x4;
typedef __attribute__((ext_vector_type(8))) short bf16x8;

typedef __attribute__((address_space(3))) unsigned char lds_b;
typedef const __attribute__((address_space(1))) unsigned char glb_b;

__device__ __forceinline__ void gload_lds16(const void* g, void* l) {
  __builtin_amdgcn_global_load_lds((glb_b*)g, (lds_b*)l, 16, 0, 0);
}

__device__ __forceinline__ unsigned short f2bf(float f) {
  union { float f; unsigned int u; } v; v.f = f;
  unsigned int r = v.u + 0x7fffu + ((v.u >> 16) & 1u);
  return (unsigned short)(r >> 16);
}

// ---------------------------------------------------------------------------
// prep_fused: blocks [0,1024) = prep_U (one per (b,mt)); [1024,3072) = prep_A.
//
// prep_U (r13 structure, VGPR-trimmed): Xl holds ONE t-group (8KB), tg loop
// re-loads the block's own x lines (L1/L2 hits after pass 1). bfr fragments
// read per-(k,tl) instead of hoisted (-24 live VGPRs -> under the 64 cliff).
// Theta fragments built directly from global Theta (L2-broadcast; r11-proven)
// -- no theta_prep kernel. Wave-private Uo staging + cooperative full-line
// stores (each b128 store inst = 8 full 128B lines). U3 layout
// [b][k][mt][ot][16] unchanged.
//
// prep_A: att tile hoisted into 16 regs (it is k-invariant; was re-read 3x).
// ---------------------------------------------------------------------------
__global__ __launch_bounds__(256) void prep_fused_k(const float* __restrict__ x,
                                                    const float* __restrict__ cheb,
                                                    const float* __restrict__ att,
                                                    const float* __restrict__ Theta,
                                                    unsigned short* __restrict__ A_ws,
                                                    unsigned short* __restrict__ U_ws) {
  __shared__ __align__(16) char smem[17408];   // U: Xl 8192 + Uo 8704 | A: 17408
  const int bid = blockIdx.x;
  const int tid = threadIdx.x;

  if (bid < 1024) {
    // ================= prep_U part =================
    unsigned short* Xl = (unsigned short*)smem;           // [tl4][m16][f64] swizzled
    unsigned short* Uo = (unsigned short*)(smem + 8192);  // [w4][o16][68]
    const int b = bid >> 5, mt = bid & 31;
    const int m0 = mt * 16;
    const int lane = tid & 63, w = tid >> 6;
    const int c = lane & 15, q = lane >> 4;
    const int og8 = lane >> 3, sub = lane & 7;

    // Theta fragments directly from global (L2-broadcast across blocks):
    // afr[k][h][j] = bf16( Theta[k][(h*4+q)*8+j][w*16+c] )
    bf16x8 afr[3][2];
#pragma unroll
    for (int k = 0; k < 3; ++k)
#pragma unroll
      for (int h = 0; h < 2; ++h) {
        const float* tp = Theta + ((size_t)k * 64 + (h * 4 + q) * 8) * 64 + w * 16 + c;
#pragma unroll
        for (int j = 0; j < 8; ++j)
          afr[k][h][j] = (short)f2bf(tp[j * 64]);
      }

    const float* xb = x + ((size_t)(b * 512 + m0)) * 768;
    const size_t ureg = ((size_t)(b * 3) * 32 + mt) * 12288;
    unsigned short* Uw = Uo + w * 1088;         // wave-private staging

    for (int tg = 0; tg < 3; ++tg) {
      if (tg) __syncthreads();   // prev-tg Xl reads done before overwrite
      // stage this tg's Xl: float4 r = f*3 + tg  (e = f*12 + tg*4 + tl)
#pragma unroll
      for (int jj = 0; jj < 4; ++jj) {
        int idx = tid + jj * 256;               // 0..1023
        int m = idx >> 6, fi = idx & 63;
        float4 v = *(const float4*)(xb + (size_t)m * 768 + (fi * 3 + tg) * 4);
        float vv[4] = {v.x, v.y, v.z, v.w};
#pragma unroll
        for (int tl = 0; tl < 4; ++tl) {
          int byte = tl * 2048 + m * 128 +
                     ((((fi >> 3) ^ (m & 7)) << 4) | ((fi & 7) << 1));
          *(unsigned short*)((char*)Xl + byte) = f2bf(vv[tl]);
        }
      }
      __syncthreads();

#pragma unroll
      for (int k = 0; k < 3; ++k) {
        f32x4 acc[4];
#pragma unroll
        for (int tl = 0; tl < 4; ++tl) {
          bf16x8 b0 = *(const bf16x8*)((char*)Xl +
                        tl * 2048 + c * 128 + (((0 + q) ^ (c & 7)) << 4));
          bf16x8 b1 = *(const bf16x8*)((char*)Xl +
                        tl * 2048 + c * 128 + (((4 + q) ^ (c & 7)) << 4));
          f32x4 a = {0.f, 0.f, 0.f, 0.f};
          a = __builtin_amdgcn_mfma_f32_16x16x32_bf16(afr[k][0], b0, a, 0, 0, 0);
          acc[tl] = __builtin_amdgcn_mfma_f32_16x16x32_bf16(afr[k][1], b1, a, 0, 0, 0);
        }
        // stage into wave-private Uo rows (2-way banks, free)
#pragma unroll
        for (int tl = 0; tl < 4; ++tl)
#pragma unroll
          for (int r = 0; r < 4; ++r)
            Uw[(q * 4 + r) * 68 + tl * 16 + c] = f2bf(acc[tl][r]);
        // cooperative full-line store: each inst = 8 full 128B lines
        unsigned short* ub2 = U_ws + ureg + (size_t)k * 393216;
#pragma unroll
        for (int i = 0; i < 2; ++i) {
          int ol = i * 8 + og8;                 // wave-local o (0..15)
          bf16x8 v = *(const bf16x8*)(Uw + ol * 68 + sub * 8);
          *(bf16x8*)(ub2 + ((w * 16 + ol) * 12 + tg * 4) * 16 + sub * 8) = v;
        }
      }
    }
  } else {
    // ================= prep_A part =================
    float (*tile)[68] = (float(*)[68])smem;      // 64x68 fp32, 17.4KB
    const int id = bid - 1024;
    const int m0 = (id & 7) * 64, n0 = ((id >> 3) & 7) * 64, b = id >> 6;
    const int rm = tid >> 2;   // 0..63
    const int c4 = tid & 3;    // 0..3
    // att tile is k-invariant: load ONCE into 16 regs (was re-read 3x)
    const float* ap = att + ((size_t)(b * 512 + m0 + rm)) * 512 + n0 + c4 * 16;
    float4 aa[4];
#pragma unroll
    for (int j = 0; j < 4; ++j) aa[j] = *(const float4*)(ap + j * 4);
    for (int k = 0; k < 3; ++k) {
      const float* cp = cheb + ((size_t)(k * 512 + m0 + rm)) * 512 + n0 + c4 * 16;
#pragma unroll
      for (int j = 0; j < 4; ++j) {
        float4 cc = *(const float4*)(cp + j * 4);
        float4 p; p.x = cc.x * aa[j].x; p.y = cc.y * aa[j].y;
        p.z = cc.z * aa[j].z; p.w = cc.w * aa[j].w;
        *(float4*)&tile[rm][c4 * 16 + j * 4] = p;
      }
      __syncthreads();
      unsigned int pk[8];
#pragma unroll
      for (int i = 0; i < 8; ++i) {
        float v0 = tile[c4 * 16 + 2 * i][rm];
        float v1 = tile[c4 * 16 + 2 * i + 1][rm];
        pk[i] = (unsigned int)f2bf(v0) | ((unsigned int)f2bf(v1) << 16);
      }
      unsigned short* op = A_ws + ((size_t)(b * 512 + n0 + rm)) * 1536 + k * 512 + m0 + c4 * 16;
      uint4 w0; w0.x = pk[0]; w0.y = pk[1]; w0.z = pk[2]; w0.w = pk[3];
      uint4 w1; w1.x = pk[4]; w1.y = pk[5]; w1.z = pk[6]; w1.w = pk[7];
      ((uint4*)op)[0] = w0;
      ((uint4*)op)[1] = w1;
      __syncthreads();
    }
  }
}

// ---------------------------------------------------------------------------
// gemm_k: out[b][n][ot] = relu( sum_{km} A_ws[b][n][km] * U3[...] )
// 128x128 tile, BK=64, 4 waves (2x2), mfma_f32_16x16x32_bf16.
// U3 [b][k][mt][ot][16]: per issue each mt-region is read as a contiguous
// 256B span (full lines). global_load_lds width=16 staging; XCD remap.
// ---------------------------------------------------------------------------
__global__ __launch_bounds__(256) void gemm_k(const unsigned short* __restrict__ A_ws,
                                              const unsigned short* __restrict__ U_ws,
                                              float* __restrict__ out) {
  __shared__ unsigned short At[128 * 64];
  __shared__ unsigned short Bt[128 * 64];
  const int hw = blockIdx.x;
  const int logical = (hw & 7) * 96 + (hw >> 3);
  const int b = logical / 24;
  const int rem = logical - b * 24;
  const int nb = (rem / 6) * 128;
  const int otb = (rem % 6) * 128;

  const int tid = threadIdx.x;
  const int lane = tid & 63, w = tid >> 6;
  const int wr = w >> 1, wc = w & 1;
  const int q = lane >> 4;   // 0..3
  const int c = lane & 15;   // 0..15

  const int rl = lane >> 3;            // row within 8-row group (== row&7)
  const int gsrc = (lane & 7) ^ rl;    // pre-swizzled source granule
  const int mi0 = (gsrc & 1) * 8;      // ushort offset within 16-m tile
  const int mtq = gsrc >> 1;           // m-tile offset within 64-m chunk
  f32x4 acc[4][4] = {};

  const int uOff = (otb + w * 8 + rl) * 16 + mi0;   // + i*32*16 per issue
  const unsigned short* aRow = A_ws + ((size_t)(b * 512 + nb + w * 8 + rl)) * 1536 + gsrc * 8;
  const int ldsRowBase = w * 8 * 64;

  for (int kt = 0; kt < 24; ++kt) {
    const int k = kt >> 3;
    const int mc = kt & 7;
    const unsigned short* uBase =
        U_ws + ((size_t)((b * 3 + k) * 32 + mc * 4 + mtq)) * 12288 + uOff;
#pragma unroll
    for (int i = 0; i < 4; ++i) {
      gload_lds16(aRow + (size_t)(i * 32) * 1536 + kt * 64, &At[ldsRowBase + i * 32 * 64]);
      gload_lds16(uBase + i * 512,                          &Bt[ldsRowBase + i * 32 * 64]);
    }
    __syncthreads();
#pragma unroll
    for (int h = 0; h < 2; ++h) {
      bf16x8 af[4], bfv[4];
#pragma unroll
      for (int mi = 0; mi < 4; ++mi) {
        int row = wr * 64 + mi * 16 + c;
        af[mi] = *(const bf16x8*)&At[row * 64 + (((h * 4 + q) ^ (row & 7)) << 3)];
      }
#pragma unroll
      for (int ni = 0; ni < 4; ++ni) {
        int row = wc * 64 + ni * 16 + c;
        bfv[ni] = *(const bf16x8*)&Bt[row * 64 + (((h * 4 + q) ^ (row & 7)) << 3)];
      }
#pragma unroll
      for (int mi = 0; mi < 4; ++mi)
#pragma unroll
        for (int ni = 0; ni < 4; ++ni)
          acc[mi][ni] = __builtin_amdgcn_mfma_f32_16x16x32_bf16(af[mi], bfv[ni], acc[mi][ni], 0, 0, 0);
    }
    __syncthreads();
  }
#pragma unroll
  for (int mi = 0; mi < 4; ++mi) {
#pragma unroll
    for (int r = 0; r < 4; ++r) {
      int n = nb + wr * 64 + mi * 16 + q * 4 + r;
      float* orow = out + ((size_t)(b * 512 + n)) * 768 + otb + wc * 64 + c;
#pragma unroll
      for (int ni = 0; ni < 4; ++ni)
        orow[ni * 16] = fmaxf(acc[mi][ni][r], 0.f);
    }
  }
}

// ---------------------------------------------------------------------------
// Fallback (exact fp32, no workspace): grid (512 n, 32 b), 256 threads.
// ---------------------------------------------------------------------------
__global__ __launch_bounds__(256) void fallback_k(const float* __restrict__ x,
                                                  const float* __restrict__ cheb,
                                                  const float* __restrict__ att,
                                                  const float* __restrict__ Theta,
                                                  float* __restrict__ out) {
  __shared__ float wsm[3][512];
  __shared__ float z[3][768];
  const int n = blockIdx.x, b = blockIdx.y;
  const int tid = threadIdx.x;
  for (int i = tid; i < 1536; i += 256) {
    int k = i >> 9, m = i & 511;
    wsm[k][m] = cheb[((size_t)(k * 512 + m)) * 512 + n] * att[((size_t)(b * 512 + m)) * 512 + n];
  }
  __syncthreads();
  float a0[3] = {0.f, 0.f, 0.f}, a1[3] = {0.f, 0.f, 0.f}, a2[3] = {0.f, 0.f, 0.f};
  const float* xb = x + (size_t)b * 512 * 768;
  for (int m = 0; m < 512; ++m) {
    float w0 = wsm[0][m], w1 = wsm[1][m], w2 = wsm[2][m];
    float x0 = xb[(size_t)m * 768 + tid];
    float x1 = xb[(size_t)m * 768 + tid + 256];
    float x2 = xb[(size_t)m * 768 + tid + 512];
    a0[0] += w0 * x0; a0[1] += w1 * x0; a0[2] += w2 * x0;
    a1[0] += w0 * x1; a1[1] += w1 * x1; a1[2] += w2 * x1;
    a2[0] += w0 * x2; a2[1] += w1 * x2; a2[2] += w2 * x2;
  }
#pragma unroll
  for (int k = 0; k < 3; ++k) {
    z[k][tid] = a0[k]; z[k][tid + 256] = a1[k]; z[k][tid + 512] = a2[k];
  }
  __syncthreads();
#pragma unroll
  for (int j = 0; j < 3; ++j) {
    int ot = tid + j * 256;
    int o = ot / 12, t = ot - o * 12;
    float s = 0.f;
    for (int k = 0; k < 3; ++k)
#pragma unroll
      for (int f = 0; f < 64; ++f)
        s += z[k][f * 12 + t] * Theta[((size_t)(k * 64 + f)) * 64 + o];
    out[((size_t)(b * 512 + n)) * 768 + ot] = fmaxf(s, 0.f);
  }
}

extern "C" void kernel_launch(void* const* d_in, const int* in_sizes, int n_in,
                              void* d_out, int out_size, void* d_ws, size_t ws_size,
                              hipStream_t stream) {
  const float* x     = (const float*)d_in[0];  // (32,512,64,12)
  const float* cheb  = (const float*)d_in[1];  // (3,512,512)
  const float* att   = (const float*)d_in[2];  // (32,512,512)
  const float* Theta = (const float*)d_in[3];  // (3,64,64)
  float* out = (float*)d_out;                  // (32,512,64,12)

  const size_t needA = (size_t)32 * 512 * 1536 * 2;       // 50,331,648
  const size_t needU = (size_t)32 * 3 * 768 * 512 * 2;    // 75,497,472

  if (ws_size >= needA + needU) {
    unsigned short* A_ws = (unsigned short*)d_ws;
    unsigned short* U_ws = (unsigned short*)((char*)d_ws + needA);
    prep_fused_k<<<dim3(3072), 256, 0, stream>>>(x, cheb, att, Theta, A_ws, U_ws);
    gemm_k<<<dim3(768), 256, 0, stream>>>(A_ws, U_ws, out);
  } else {
    fallback_k<<<dim3(512, 32), 256, 0, stream>>>(x, cheb, att, Theta, out);
  }
}